// Round 1
// baseline (888.117 us; speedup 1.0000x reference)
//
#include <hip/hip_runtime.h>
#include <math.h>

#define NN 50000
#define NE 800000
#define FIN 128
#define HEADS 4
#define HID 32
#define D1 128
#define NCLS 16
#define NEG 0.2f
#define NINF (-3.402823466e38f)

// ---------------- CSR build ----------------
__global__ void k_count(const int* __restrict__ dst, int* __restrict__ counts) {
  int j = blockIdx.x * 256 + threadIdx.x;
  if (j < NE) atomicAdd(&counts[dst[j]], 1);
}

__global__ void k_scan(const int* __restrict__ counts, int* __restrict__ starts,
                       int* __restrict__ cursor) {
  __shared__ int sums[1024];
  int tid = threadIdx.x;
  const int CH = (NN + 1023) / 1024;
  int base = tid * CH;
  int s = 0;
  for (int i = 0; i < CH; i++) { int idx = base + i; if (idx < NN) s += counts[idx]; }
  sums[tid] = s;
  __syncthreads();
  for (int off = 1; off < 1024; off <<= 1) {
    int v = (tid >= off) ? sums[tid - off] : 0;
    __syncthreads();
    sums[tid] += v;
    __syncthreads();
  }
  int run = (tid == 0) ? 0 : sums[tid - 1];
  for (int i = 0; i < CH; i++) {
    int idx = base + i;
    if (idx < NN) { starts[idx] = run; cursor[idx] = run; run += counts[idx]; }
  }
}

__global__ void k_scatter(const int* __restrict__ src, const int* __restrict__ dst,
                          int* __restrict__ cursor, int* __restrict__ eperm,
                          int* __restrict__ sperm) {
  int j = blockIdx.x * 256 + threadIdx.x;
  if (j < NE) {
    int p = atomicAdd(&cursor[dst[j]], 1);
    eperm[p] = j;
    sperm[p] = src[j];
  }
}

// ---------------- fp32 tiled GEMM ----------------
// ACT: 0=none, 1=elu
template <int BM, int BN, int BK, int TM, int TN, int ACT>
__global__ __launch_bounds__(256) void k_gemm(const float* __restrict__ A,
                                              const float* __restrict__ B,
                                              const float* __restrict__ bias,
                                              float* __restrict__ C, int M, int N, int K) {
  constexpr int NT = (BM / TM) * (BN / TN);
  static_assert(NT == 256, "block must be 256 threads");
  __shared__ float As[BK][BM + 4];
  __shared__ float Bs[BK][BN];
  int tid = threadIdx.x;
  int bm = blockIdx.y * BM, bn = blockIdx.x * BN;
  constexpr int TX = BN / TN;
  int tn = (tid % TX) * TN;
  int tm = (tid / TX) * TM;
  float acc[TM][TN];
#pragma unroll
  for (int i = 0; i < TM; i++)
#pragma unroll
    for (int j = 0; j < TN; j++) acc[i][j] = 0.f;

  for (int k0 = 0; k0 < K; k0 += BK) {
    constexpr int AV = BM * BK / 4;
    for (int i = tid; i < AV; i += NT) {
      int r = i / (BK / 4);
      int c4 = (i % (BK / 4)) * 4;
      float4 v = make_float4(0.f, 0.f, 0.f, 0.f);
      int gr = bm + r;
      if (gr < M) v = *(const float4*)(A + (size_t)gr * K + k0 + c4);
      As[c4 + 0][r] = v.x; As[c4 + 1][r] = v.y; As[c4 + 2][r] = v.z; As[c4 + 3][r] = v.w;
    }
    constexpr int BV = BK * BN / 4;
    for (int i = tid; i < BV; i += NT) {
      int r = i / (BN / 4), c4 = (i % (BN / 4)) * 4;
      float4 v = *(const float4*)(B + (size_t)(k0 + r) * N + bn + c4);
      Bs[r][c4 + 0] = v.x; Bs[r][c4 + 1] = v.y; Bs[r][c4 + 2] = v.z; Bs[r][c4 + 3] = v.w;
    }
    __syncthreads();
#pragma unroll
    for (int kk = 0; kk < BK; kk++) {
      float ra[TM], rb[TN];
#pragma unroll
      for (int i = 0; i < TM; i++) ra[i] = As[kk][tm + i];
#pragma unroll
      for (int j = 0; j < TN; j++) rb[j] = Bs[kk][tn + j];
#pragma unroll
      for (int i = 0; i < TM; i++)
#pragma unroll
        for (int j = 0; j < TN; j++) acc[i][j] += ra[i] * rb[j];
    }
    __syncthreads();
  }
#pragma unroll
  for (int i = 0; i < TM; i++) {
    int gr = bm + tm + i;
    if (gr >= M) continue;
#pragma unroll
    for (int j = 0; j < TN; j++) {
      float v = acc[i][j];
      if (bias) v += bias[bn + tn + j];
      if (ACT == 1) v = v > 0.f ? v : expm1f(v);
      C[(size_t)gr * N + bn + tn + j] = v;
    }
  }
}

// ---------------- edge scores ----------------
template <int H, int C>
__global__ void k_scores(const float* __restrict__ xl, const float* __restrict__ xr,
                         const float* __restrict__ att, const int* __restrict__ sperm,
                         const int* __restrict__ eperm, const int* __restrict__ dst,
                         float* __restrict__ eout) {
  long long t = (long long)blockIdx.x * 256 + threadIdx.x;
  if (t >= (long long)NE * H) return;
  int p = (int)(t / H), h = (int)(t - (long long)p * H);
  int s = sperm[p];
  int d = dst[eperm[p]];
  const float* a = xl + (size_t)s * (H * C) + h * C;
  const float* b = xr + (size_t)d * (H * C) + h * C;
  const float* at = att + h * C;
  float acc = 0.f;
#pragma unroll
  for (int c = 0; c < C; c += 4) {
    float4 va = *(const float4*)(a + c);
    float4 vb = *(const float4*)(b + c);
    float4 vt = *(const float4*)(at + c);
    float v;
    v = va.x + vb.x; acc += (v > 0.f ? v : NEG * v) * vt.x;
    v = va.y + vb.y; acc += (v > 0.f ? v : NEG * v) * vt.y;
    v = va.z + vb.z; acc += (v > 0.f ? v : NEG * v) * vt.z;
    v = va.w + vb.w; acc += (v > 0.f ? v : NEG * v) * vt.w;
  }
  eout[(size_t)p * H + h] = acc;
}

// ---------------- top-k + dual masked softmax (in-place weights) ----------------
// Reference tie-break: stable sort => within equal scores, smaller original
// edge index wins. Lexicographic order: (score desc, edge_id asc).
// Output: kept edges get +alpha, noise edges get -alpha_n.
template <int H>
__global__ void k_topk(float* __restrict__ e, const int* __restrict__ eperm,
                       const int* __restrict__ starts, const int* __restrict__ counts,
                       const int* __restrict__ kptr) {
  int t = blockIdx.x * 256 + threadIdx.x;
  if (t >= NN * H) return;
  int d = t / H, h = t - d * H;
  int st = starts[d], deg = counts[d];
  if (deg == 0) return;
  int k = kptr[0];

  // pass: global max (lexicographic)
  float bv = NINF; int bi = 0x7fffffff;
  for (int q = 0; q < deg; q++) {
    float v = e[(size_t)(st + q) * H + h];
    int id = eperm[st + q];
    if (v > bv || (v == bv && id < bi)) { bv = v; bi = id; }
  }
  float m_keep = bv;
  int lim = k < deg ? k : deg;
  for (int nsel = 1; nsel < lim; nsel++) {
    float cv = NINF; int ci = 0x7fffffff;
    for (int q = 0; q < deg; q++) {
      float v = e[(size_t)(st + q) * H + h];
      int id = eperm[st + q];
      bool ltb = (v < bv) || (v == bv && id > bi);
      bool gtc = (v > cv) || (v == cv && id < ci);
      if (ltb && gtc) { cv = v; ci = id; }
    }
    bv = cv; bi = ci;
  }
  float thrv; int thri; float m_noise = 0.f;
  if (deg > k) {
    thrv = bv; thri = bi;  // k-th largest
    float cv = NINF;
    for (int q = 0; q < deg; q++) {
      float v = e[(size_t)(st + q) * H + h];
      int id = eperm[st + q];
      if (((v < thrv) || (v == thrv && id > thri)) && v > cv) cv = v;
    }
    m_noise = cv;  // max of noise set (deg>k => nonempty)
  } else {
    thrv = NINF; thri = 0x7fffffff;  // keep everything
  }
  float sk = 0.f, sn = 0.f;
  for (int q = 0; q < deg; q++) {
    float v = e[(size_t)(st + q) * H + h];
    int id = eperm[st + q];
    bool kept = (v > thrv) || (v == thrv && id <= thri);
    if (kept) sk += expf(v - m_keep); else sn += expf(v - m_noise);
  }
  float ik = 1.f / (sk + 1e-16f), inn = 1.f / (sn + 1e-16f);
  for (int q = 0; q < deg; q++) {
    size_t idx = (size_t)(st + q) * H + h;
    float v = e[idx];
    int id = eperm[st + q];
    bool kept = (v > thrv) || (v == thrv && id <= thri);
    e[idx] = kept ? expf(v - m_keep) * ik : -(expf(v - m_noise) * inn);
  }
}

// ---------------- aggregation layer 1 (block per dst, lane = channel) ----------------
__global__ __launch_bounds__(128) void k_aggr1(const float* __restrict__ xl,
                                               const float* __restrict__ w,
                                               const int* __restrict__ sperm,
                                               const int* __restrict__ starts,
                                               const int* __restrict__ counts,
                                               const float* __restrict__ b1,
                                               float* __restrict__ hout,
                                               float* __restrict__ nout) {
  int d = blockIdx.x;
  int t = threadIdx.x;  // channel = h*32+c
  int st = starts[d], deg = counts[d];
  int h = t >> 5;
  float ao = 0.f, an = 0.f;
  for (int q = 0; q < deg; q++) {
    int s = sperm[st + q];
    float wv = w[(size_t)(st + q) * HEADS + h];
    float xv = xl[(size_t)s * D1 + t];
    if (wv > 0.f) ao += wv * xv; else an -= wv * xv;
  }
  float o = ao + b1[t];
  hout[(size_t)d * D1 + t] = o > 0.f ? o : expm1f(o);  // h = elu(out+b1)
  nout[(size_t)d * D1 + t] = an + b1[t];               // noise1 = noise+b1
}

// ---------------- aggregation layer 2 (thread per (dst, class)) ----------------
__global__ void k_aggr2(const float* __restrict__ xl2, const float* __restrict__ w,
                        const int* __restrict__ sperm, const int* __restrict__ starts,
                        const int* __restrict__ counts, const float* __restrict__ b2,
                        float* __restrict__ out2, float* __restrict__ noise2) {
  int t = blockIdx.x * 256 + threadIdx.x;
  if (t >= NN * NCLS) return;
  int d = t / NCLS, c = t - d * NCLS;
  int st = starts[d], deg = counts[d];
  float ao = 0.f, an = 0.f;
  for (int q = 0; q < deg; q++) {
    int s = sperm[st + q];
    float wv = w[st + q];
    float xv = xl2[(size_t)s * NCLS + c];
    if (wv > 0.f) ao += wv * xv; else an -= wv * xv;
  }
  out2[t] = ao + b2[c];
  noise2[t] = an + b2[c];
}

// ---------------- row log_softmax over 16 ----------------
__global__ void k_lsm(const float* __restrict__ in, float* __restrict__ out) {
  int r = blockIdx.x * 256 + threadIdx.x;
  if (r >= NN) return;
  const float4* p = (const float4*)(in + (size_t)r * NCLS);
  float4 a = p[0], b = p[1], c = p[2], d4 = p[3];
  float vals[16] = {a.x, a.y, a.z, a.w, b.x, b.y, b.z, b.w,
                    c.x, c.y, c.z, c.w, d4.x, d4.y, d4.z, d4.w};
  float m = vals[0];
#pragma unroll
  for (int i = 1; i < 16; i++) m = fmaxf(m, vals[i]);
  float s = 0.f;
#pragma unroll
  for (int i = 0; i < 16; i++) s += expf(vals[i] - m);
  float l = m + logf(s);
  float* op = out + (size_t)r * NCLS;
#pragma unroll
  for (int i = 0; i < 16; i++) op[i] = vals[i] - l;
}

extern "C" void kernel_launch(void* const* d_in, const int* in_sizes, int n_in,
                              void* d_out, int out_size, void* d_ws, size_t ws_size,
                              hipStream_t stream) {
  (void)in_sizes; (void)n_in; (void)out_size; (void)ws_size;
  const float* x    = (const float*)d_in[0];
  const int*   ei   = (const int*)d_in[1];
  const int*   kptr = (const int*)d_in[2];
  const float* Wl1  = (const float*)d_in[3];
  const float* Wr1  = (const float*)d_in[4];
  const float* att1 = (const float*)d_in[5];
  const float* b1   = (const float*)d_in[6];
  const float* Wl2  = (const float*)d_in[7];
  const float* Wr2  = (const float*)d_in[8];
  const float* att2 = (const float*)d_in[9];
  const float* b2   = (const float*)d_in[10];
  const float* l1w  = (const float*)d_in[11];
  const float* l1b  = (const float*)d_in[12];
  const float* l2w  = (const float*)d_in[13];
  const float* l2b  = (const float*)d_in[14];
  const int* srcv = ei;
  const int* dstv = ei + NE;

  char* wp = (char*)d_ws;
  auto alloc = [&](size_t n) { char* p = wp; wp += (n + 255) & ~(size_t)255; return p; };
  float* xl1    = (float*)alloc((size_t)NN * D1 * 4);  // xl1, alive through aggr1
  float* bufB   = (float*)alloc((size_t)NN * D1 * 4);  // xr1, then h
  float* noise1 = (float*)alloc((size_t)NN * D1 * 4);  // noise1, then n1/out2/noise2
  float* t1     = (float*)alloc((size_t)NN * D1 * 4);  // mlp hidden, then xl2/xr2
  float* ebuf   = (float*)alloc((size_t)NE * HEADS * 4);  // e then w (in-place)
  int* counts = (int*)alloc((size_t)NN * 4);
  int* starts = (int*)alloc((size_t)NN * 4);
  int* cursor = (int*)alloc((size_t)NN * 4);
  int* eperm  = (int*)alloc((size_t)NE * 4);
  int* sperm  = (int*)alloc((size_t)NE * 4);

  // CSR build
  hipMemsetAsync(counts, 0, (size_t)NN * 4, stream);
  k_count<<<(NE + 255) / 256, 256, 0, stream>>>(dstv, counts);
  k_scan<<<1, 1024, 0, stream>>>(counts, starts, cursor);
  k_scatter<<<(NE + 255) / 256, 256, 0, stream>>>(srcv, dstv, cursor, eperm, sperm);

  // Layer 1 node transforms
  dim3 gbig(D1 / 64, (NN + 63) / 64);
  k_gemm<64, 64, 32, 4, 4, 0><<<gbig, 256, 0, stream>>>(x, Wl1, nullptr, xl1, NN, D1, FIN);
  k_gemm<64, 64, 32, 4, 4, 0><<<gbig, 256, 0, stream>>>(x, Wr1, nullptr, bufB, NN, D1, FIN);

  // Layer 1 edges
  k_scores<HEADS, HID><<<(NE * HEADS + 255) / 256, 256, 0, stream>>>(
      xl1, bufB, att1, sperm, eperm, dstv, ebuf);
  k_topk<HEADS><<<(NN * HEADS + 255) / 256, 256, 0, stream>>>(ebuf, eperm, starts, counts, kptr);
  k_aggr1<<<NN, 128, 0, stream>>>(xl1, ebuf, sperm, starts, counts, b1, bufB, noise1);

  // MLP on noise1
  k_gemm<64, 64, 32, 4, 4, 1><<<gbig, 256, 0, stream>>>(noise1, l1w, l1b, t1, NN, 128, 128);
  float* n1v    = noise1;
  float* out2   = noise1 + (size_t)NN * NCLS;
  float* noise2 = noise1 + (size_t)2 * NN * NCLS;
  dim3 gsm(1, (NN + 127) / 128);
  k_gemm<128, 16, 32, 4, 2, 0><<<gsm, 256, 0, stream>>>(t1, l2w, l2b, n1v, NN, NCLS, 128);

  // Layer 2 node transforms (overwrite t1 after mlp done)
  float* xl2 = t1;
  float* xr2 = t1 + (size_t)NN * NCLS;
  k_gemm<128, 16, 32, 4, 2, 0><<<gsm, 256, 0, stream>>>(bufB, Wl2, nullptr, xl2, NN, NCLS, D1);
  k_gemm<128, 16, 32, 4, 2, 0><<<gsm, 256, 0, stream>>>(bufB, Wr2, nullptr, xr2, NN, NCLS, D1);

  // Layer 2 edges
  k_scores<1, NCLS><<<(NE + 255) / 256, 256, 0, stream>>>(xl2, xr2, att2, sperm, eperm, dstv, ebuf);
  k_topk<1><<<(NN + 255) / 256, 256, 0, stream>>>(ebuf, eperm, starts, counts, kptr);
  k_aggr2<<<(NN * NCLS + 255) / 256, 256, 0, stream>>>(xl2, ebuf, sperm, starts, counts, b2,
                                                       out2, noise2);

  // Outputs
  float* o = (float*)d_out;
  k_lsm<<<(NN + 255) / 256, 256, 0, stream>>>(out2, o);
  k_lsm<<<(NN + 255) / 256, 256, 0, stream>>>(n1v, o + (size_t)NN * NCLS);
  k_lsm<<<(NN + 255) / 256, 256, 0, stream>>>(noise2, o + (size_t)2 * NN * NCLS);
}